// Round 8
// baseline (808.845 us; speedup 1.0000x reference)
//
#include <hip/hip_runtime.h>
#include <hip/hip_fp16.h>
#include <cstddef>

static constexpr int BTOT = 131072;     // B*T
static constexpr int RESO_ = 128;
static constexpr int R2_ = RESO_ * RESO_;   // 16384
static constexpr int NBIN = 4 * R2_;        // B*R2 = 65536
static constexpr int HDIM = 128;
static constexpr int CDIM = 64;

typedef __attribute__((ext_vector_type(8))) short short8;
typedef _Float16 half8 __attribute__((ext_vector_type(8)));
typedef __attribute__((ext_vector_type(4))) float floatx4;

__device__ __forceinline__ unsigned short f2h(float f) {
  return __half_as_ushort(__float2half(f));   // RTN
}
__device__ __forceinline__ float h2f(unsigned short h) {
  return __half2float(__ushort_as_half(h));
}
// relu on packed f16: sign bit = bit15, so int16 max-with-0 works (+0.0 = 0x0000)
__device__ __forceinline__ short8 relu8(short8 v) {
#pragma unroll
  for (int i = 0; i < 8; ++i) v[i] = (v[i] < (short)0) ? (short)0 : v[i];
  return v;
}

// ---------- bin indices for the 3 planes ----------
__global__ __launch_bounds__(256) void k_idx(const float* __restrict__ p,
                                             int* __restrict__ idx) {
  int pt = blockIdx.x * 256 + threadIdx.x;
  const float DIVC = (float)(1.0 + 0.1 + 1e-5);
  const float HI = (float)(1.0 - 1e-5);
  float x = p[pt * 3 + 0], y = p[pt * 3 + 1], z = p[pt * 3 + 2];
  float nx = fminf(fmaxf(x / DIVC + 0.5f, 0.0f), HI);
  float ny = fminf(fmaxf(y / DIVC + 0.5f, 0.0f), HI);
  float nz = fminf(fmaxf(z / DIVC + 0.5f, 0.0f), HI);
  int ix = (int)(nx * (float)RESO_);
  int iy = (int)(ny * (float)RESO_);
  int iz = (int)(nz * (float)RESO_);
  int off = (pt >> 15) * R2_;
  idx[0 * BTOT + pt] = ix + RESO_ * iz + off; // xz
  idx[1 * BTOT + pt] = ix + RESO_ * iy + off; // xy
  idx[2 * BTOT + pt] = iy + RESO_ * iz + off; // yz
}

// ---------- bin list construction ----------
__global__ __launch_bounds__(256) void k_count(const int* __restrict__ idx,
                                               int* __restrict__ cnt) {
  int e = blockIdx.x * 256 + threadIdx.x;    // 3*BTOT
  int pl = e / BTOT;
  atomicAdd(&cnt[pl * NBIN + idx[e]], 1);
}

__global__ __launch_bounds__(1024) void k_scan(const int* __restrict__ cnt,
                                               int* __restrict__ starts,
                                               int* __restrict__ cursor) {
  __shared__ int part[1024];
  int pl = blockIdx.x;
  int t = threadIdx.x;
  const int* c = cnt + pl * NBIN;
  int base = t * 64;
  int s = 0;
  for (int i = 0; i < 64; ++i) s += c[base + i];
  part[t] = s;
  __syncthreads();
  for (int off = 1; off < 1024; off <<= 1) {
    int v = (t >= off) ? part[t - off] : 0;
    __syncthreads();
    part[t] += v;
    __syncthreads();
  }
  int run = (t == 0) ? 0 : part[t - 1];
  int* st = starts + pl * (NBIN + 1);
  int* cur = cursor + pl * NBIN;
  for (int i = 0; i < 64; ++i) {
    st[base + i] = run;
    cur[base + i] = run;
    run += c[base + i];
  }
  if (t == 1023) st[NBIN] = run;
}

__global__ __launch_bounds__(256) void k_place(const int* __restrict__ idx,
                                               int* __restrict__ cursor,
                                               int* __restrict__ plist) {
  int e = blockIdx.x * 256 + threadIdx.x;    // 3*BTOT
  int pl = e / BTOT, pt = e - pl * BTOT;
  int pos = atomicAdd(&cursor[pl * NBIN + idx[e]], 1);
  plist[(size_t)pl * BTOT + pos] = pt;
}

// ---------- fc_pos -> f16 netA / poolB ----------
__global__ __launch_bounds__(256) void k_fcpos(const float* __restrict__ p,
                                               const float* __restrict__ w,
                                               const float* __restrict__ b,
                                               unsigned short* __restrict__ netA,
                                               unsigned short* __restrict__ poolB) {
  int e = blockIdx.x * 256 + threadIdx.x;
  int pt = e >> 8, col = e & 255;
  float x0 = p[pt * 3 + 0], x1 = p[pt * 3 + 1], x2 = p[pt * 3 + 2];
  float v = b[col] + x0 * w[col] + x1 * w[256 + col] + x2 * w[512 + col];
  unsigned short h = f2h(v);
  if (col < HDIM) netA[(size_t)pt * HDIM + col] = h;
  else            poolB[(size_t)pt * HDIM + (col - HDIM)] = h;
}

// ---------- weight packing into MFMA B-fragment order (single f16) ----------
__global__ __launch_bounds__(256) void k_pack(const float* __restrict__ bw0,
                                              const float* __restrict__ bw1,
                                              const float* __restrict__ bws,
                                              unsigned short* __restrict__ P1,
                                              unsigned short* __restrict__ P2) {
  int t = blockIdx.x * 256 + threadIdx.x;
  if (t >= 5 * 20 * 8 * 64) return;
  int lane = t & 63;
  int r = t >> 6;
  int nt = r & 7; r >>= 3;
  int kb20 = r % 20;
  int l = r / 20;
  int quad = lane >> 4;
  int n = nt * 16 + (lane & 15);
#pragma unroll
  for (int j = 0; j < 8; ++j) {
    if (kb20 < 8) {
      int k = kb20 * 32 + quad * 8 + j;
      float v = bw0[((size_t)l * 256 + k) * 128 + n];
      size_t didx = (((size_t)(l * 8 + kb20) * 8 + nt) * 64 + lane) * 8 + j;
      P1[didx] = f2h(v);
    } else {
      int kb = kb20 - 8;
      int k = kb * 32 + quad * 8 + j;
      float v = (k < 256) ? bws[((size_t)l * 256 + k) * 128 + n]
                          : bw1[((size_t)l * 128 + (k - 256)) * 128 + n];
      size_t didx = (((size_t)(l * 12 + kb) * 8 + nt) * 64 + lane) * 8 + j;
      P2[didx] = f2h(v);
    }
  }
}

// ---------- fc_c weight packing: P3[(kb*4+nt)*64+lane][j] ----------
__global__ __launch_bounds__(256) void k_packc(const float* __restrict__ fccw,
                                               unsigned short* __restrict__ P3) {
  int t = blockIdx.x * 256 + threadIdx.x;    // 16 frags x 64 lanes
  if (t >= 16 * 64) return;
  int lane = t & 63;
  int fr = t >> 6;
  int nt = fr & 3, kb = fr >> 2;
  int quad = lane >> 4;
  int n = nt * 16 + (lane & 15);
#pragma unroll
  for (int j = 0; j < 8; ++j) {
    int k = kb * 32 + quad * 8 + j;
    P3[((size_t)fr * 64 + lane) * 8 + j] = f2h(fccw[(size_t)k * 64 + n]);
  }
}

// ---------- list-based pooling max (f16), 8 bins/wave interleaved ----------
// grid (NBIN/32, 3); block 256 = 4 waves x 8 bins. Lane covers 2 channels.
__global__ __launch_bounds__(256) void k_poolmax(const unsigned short* __restrict__ net,
                                                 const int* __restrict__ starts,
                                                 const int* __restrict__ plist,
                                                 unsigned short* __restrict__ seg) {
  int tid = threadIdx.x;
  int pl = blockIdx.y;
  int wv = tid >> 6, lane = tid & 63;
  int bin0 = blockIdx.x * 32 + wv * 8;
  const int* st = starts + pl * (NBIN + 1) + bin0;
  int sa[9];
#pragma unroll
  for (int i = 0; i < 9; ++i) sa[i] = st[i];
  const int* pli = plist + (size_t)pl * BTOT;
  float v0[8], v1[8];
#pragma unroll
  for (int i = 0; i < 8; ++i) { v0[i] = -3.4e38f; v1[i] = -3.4e38f; }
  int lmax = 0;
#pragma unroll
  for (int i = 0; i < 8; ++i) lmax = max(lmax, sa[i + 1] - sa[i]);
  for (int k = 0; k < lmax; ++k) {
#pragma unroll
    for (int i = 0; i < 8; ++i) {         // 8 independent load chains in flight
      int t = sa[i] + k;
      int kk = max(min(t, sa[i + 1] - 1), 0);
      int pid = pli[kk];
      unsigned u = *(const unsigned*)(net + (size_t)pid * 128 + lane * 2);
      if (t < sa[i + 1]) {
        v0[i] = fmaxf(v0[i], h2f((unsigned short)(u & 0xffffu)));
        v1[i] = fmaxf(v1[i], h2f((unsigned short)(u >> 16)));
      }
    }
  }
#pragma unroll
  for (int i = 0; i < 8; ++i) {
    if (sa[i + 1] > sa[i]) {               // empty bins never gathered
      unsigned o = (unsigned)f2h(v0[i]) | ((unsigned)f2h(v1[i]) << 16);
      *(unsigned*)(seg + ((size_t)pl * NBIN + bin0 + i) * 128 + lane * 2) = o;
    }
  }
}

// ---------- fused resblock, direct global A-frags + LDS gather half ----------
// 32 rows/block, 4 waves = col quarters; each wave 32 rows x 32 cols.
// netA/poolB halves are read as MFMA A-fragments DIRECTLY from global (their
// row-major f16 layout == fragment layout); only the mode-1 gather result and
// the intermediate t go through LDS. 17.4 KB LDS + <=64 VGPR -> 8 blocks/CU.
__global__ __launch_bounds__(256, 8) void k_resblock(
    unsigned short* __restrict__ netA, const unsigned short* __restrict__ segB,
    const int* __restrict__ idx, int mode,
    const unsigned short* __restrict__ P1, const unsigned short* __restrict__ P2,
    const float* __restrict__ b0, const float* __restrict__ b1,
    const unsigned short* __restrict__ P3, const float* __restrict__ bc,
    unsigned short* __restrict__ cOut) {
  __shared__ __align__(16) unsigned short xh[32][136];   // pooled half (mode 1)
  __shared__ __align__(16) unsigned short th[32][136];
  int tid = threadIdx.x;
  int rows0 = blockIdx.x * 32;

  if (mode == 1) {
    // stage A: pooled = sum of 3 plane maxima (packed f16 adds)
#pragma unroll
    for (int i = 0; i < 2; ++i) {
      int g8 = i * 256 + tid;             // [0,512): 32 rows x 16 groups
      int row = g8 >> 4;
      int cc = (g8 & 15) * 8;
      int grow = rows0 + row;
      int i0 = idx[grow], i1 = idx[BTOT + grow], i2 = idx[2 * BTOT + grow];
      short8 a = *(const short8*)(segB + (size_t)i0 * 128 + cc);
      short8 b8 = *(const short8*)(segB + (size_t)NBIN * 128 + (size_t)i1 * 128 + cc);
      short8 c8 = *(const short8*)(segB + (size_t)2 * NBIN * 128 + (size_t)i2 * 128 + cc);
      half8 s = *(half8*)&a + *(half8*)&b8 + *(half8*)&c8;
      *(short8*)&xh[row][cc] = *(short8*)&s;
    }
    __syncthreads();
  }

  int lane = tid & 63;
  int cg = tid >> 6;               // col quarter [0,4)
  int quad = lane >> 4;
  int m0 = lane & 15;

  // ---- stage 1: t = relu(x) @ w0 + b0 ----
  floatx4 acc[2][2] = {};
  for (int kb = 0; kb < 8; ++kb) {
    short8 as0, as1;
    if (kb < 4) {
      as0 = *(const short8*)(netA + (size_t)(rows0 + m0) * 128 + kb * 32 + quad * 8);
      as1 = *(const short8*)(netA + (size_t)(rows0 + m0 + 16) * 128 + kb * 32 + quad * 8);
    } else if (mode == 0) {
      as0 = *(const short8*)(segB + (size_t)(rows0 + m0) * 128 + (kb - 4) * 32 + quad * 8);
      as1 = *(const short8*)(segB + (size_t)(rows0 + m0 + 16) * 128 + (kb - 4) * 32 + quad * 8);
    } else {
      as0 = *(const short8*)&xh[m0][(kb - 4) * 32 + quad * 8];
      as1 = *(const short8*)&xh[m0 + 16][(kb - 4) * 32 + quad * 8];
    }
    as0 = relu8(as0);
    as1 = relu8(as1);
    const short8* wf = (const short8*)P1 + ((size_t)(kb * 8 + cg * 2) * 64 + lane);
#pragma unroll
    for (int nti = 0; nti < 2; ++nti) {
      short8 bs = wf[nti * 64];
      half8 bw = *(half8*)&bs;
      acc[0][nti] = __builtin_amdgcn_mfma_f32_16x16x32_f16(*(half8*)&as0, bw, acc[0][nti], 0, 0, 0);
      acc[1][nti] = __builtin_amdgcn_mfma_f32_16x16x32_f16(*(half8*)&as1, bw, acc[1][nti], 0, 0, 0);
    }
  }
  // epilogue 1: bias + relu -> th (f16)
#pragma unroll
  for (int rs = 0; rs < 2; ++rs) {
#pragma unroll
    for (int nti = 0; nti < 2; ++nti) {
      int col = cg * 32 + nti * 16 + (lane & 15);
      float bb = b0[col];
#pragma unroll
      for (int r = 0; r < 4; ++r) {
        int row = rs * 16 + quad * 4 + r;
        th[row][col] = f2h(fmaxf(acc[rs][nti][r] + bb, 0.0f));
      }
    }
  }
  __syncthreads();

  // ---- stage 2: out = x @ ws + relu_t @ w1 + b1 ----
  floatx4 acc2[2][2] = {};
  for (int kb = 0; kb < 12; ++kb) {
    short8 as0, as1;
    if (kb < 4) {
      as0 = *(const short8*)(netA + (size_t)(rows0 + m0) * 128 + kb * 32 + quad * 8);
      as1 = *(const short8*)(netA + (size_t)(rows0 + m0 + 16) * 128 + kb * 32 + quad * 8);
    } else if (kb < 8) {
      if (mode == 0) {
        as0 = *(const short8*)(segB + (size_t)(rows0 + m0) * 128 + (kb - 4) * 32 + quad * 8);
        as1 = *(const short8*)(segB + (size_t)(rows0 + m0 + 16) * 128 + (kb - 4) * 32 + quad * 8);
      } else {
        as0 = *(const short8*)&xh[m0][(kb - 4) * 32 + quad * 8];
        as1 = *(const short8*)&xh[m0 + 16][(kb - 4) * 32 + quad * 8];
      }
    } else {
      as0 = *(const short8*)&th[m0][(kb - 8) * 32 + quad * 8];
      as1 = *(const short8*)&th[m0 + 16][(kb - 8) * 32 + quad * 8];
    }
    const short8* wf = (const short8*)P2 + ((size_t)(kb * 8 + cg * 2) * 64 + lane);
#pragma unroll
    for (int nti = 0; nti < 2; ++nti) {
      short8 bs = wf[nti * 64];
      half8 bw = *(half8*)&bs;
      acc2[0][nti] = __builtin_amdgcn_mfma_f32_16x16x32_f16(*(half8*)&as0, bw, acc2[0][nti], 0, 0, 0);
      acc2[1][nti] = __builtin_amdgcn_mfma_f32_16x16x32_f16(*(half8*)&as1, bw, acc2[1][nti], 0, 0, 0);
    }
  }
  __syncthreads();    // all waves done reading netA before in-place overwrite

  if (!cOut) {
    // epilogue 2: bias + f16 store (in-place; block owns rows)
#pragma unroll
    for (int rs = 0; rs < 2; ++rs) {
#pragma unroll
      for (int nti = 0; nti < 2; ++nti) {
        int col = cg * 32 + nti * 16 + (lane & 15);
        float bb = b1[col];
#pragma unroll
        for (int r = 0; r < 4; ++r) {
          int row = rows0 + rs * 16 + quad * 4 + r;
          netA[(size_t)row * 128 + col] = f2h(acc2[rs][nti][r] + bb);
        }
      }
    }
  } else {
    // fused fc_c: round-trip net through xh, then 8 MFMAs per wave
#pragma unroll
    for (int rs = 0; rs < 2; ++rs) {
#pragma unroll
      for (int nti = 0; nti < 2; ++nti) {
        int col = cg * 32 + nti * 16 + (lane & 15);
        float bb = b1[col];
#pragma unroll
        for (int r = 0; r < 4; ++r) {
          int row = rs * 16 + quad * 4 + r;
          xh[row][col] = f2h(acc2[rs][nti][r] + bb);
        }
      }
    }
    __syncthreads();
    floatx4 acc3[2] = {};
    for (int kb = 0; kb < 4; ++kb) {
      short8 as0 = *(const short8*)&xh[m0][kb * 32 + quad * 8];
      short8 as1 = *(const short8*)&xh[m0 + 16][kb * 32 + quad * 8];
      short8 bs = *((const short8*)P3 + ((size_t)(kb * 4 + cg) * 64 + lane));
      half8 bw = *(half8*)&bs;
      acc3[0] = __builtin_amdgcn_mfma_f32_16x16x32_f16(*(half8*)&as0, bw, acc3[0], 0, 0, 0);
      acc3[1] = __builtin_amdgcn_mfma_f32_16x16x32_f16(*(half8*)&as1, bw, acc3[1], 0, 0, 0);
    }
    int col = cg * 16 + (lane & 15);
    float bb = bc[col];
#pragma unroll
    for (int rs = 0; rs < 2; ++rs) {
#pragma unroll
      for (int r = 0; r < 4; ++r) {
        int row = rows0 + rs * 16 + quad * 4 + r;
        cOut[(size_t)row * 64 + col] = f2h(acc3[rs][r] + bb);
      }
    }
  }
}

// ---------- fused list-based scatter-mean + transposed output ----------
// 8 bins per wave interleaved for load ILP.
__global__ __launch_bounds__(256) void k_meanout(const unsigned short* __restrict__ c,
                                                 const int* __restrict__ starts,
                                                 const int* __restrict__ plist,
                                                 float* __restrict__ out) {
  __shared__ float tile[64][65];
  int tid = threadIdx.x;
  int pb = blockIdx.y;                 // pl*4 + b
  int pl = pb >> 2;
  int b = pb & 3;
  int bin0 = blockIdx.x * 64;
  int w = tid >> 6, lane = tid & 63;
  const int* st = starts + pl * (NBIN + 1) + b * R2_ + bin0 + w * 16;
  const int* pli = plist + (size_t)pl * BTOT;
  for (int grp = 0; grp < 2; ++grp) {
    int sa[9];
#pragma unroll
    for (int i = 0; i < 9; ++i) sa[i] = st[grp * 8 + i];
    float sum[8] = {0.f, 0.f, 0.f, 0.f, 0.f, 0.f, 0.f, 0.f};
    int lmax = 0;
#pragma unroll
    for (int i = 0; i < 8; ++i) lmax = max(lmax, sa[i + 1] - sa[i]);
    for (int k = 0; k < lmax; ++k) {
#pragma unroll
      for (int i = 0; i < 8; ++i) {
        int t = sa[i] + k;
        int kk = max(min(t, sa[i + 1] - 1), 0);
        int pid = pli[kk];
        float v = h2f(c[(size_t)pid * 64 + lane]);
        if (t < sa[i + 1]) sum[i] += v;
      }
    }
#pragma unroll
    for (int i = 0; i < 8; ++i) {
      int lb = w * 16 + grp * 8 + i;
      tile[lb][lane] = sum[i] / fmaxf((float)(sa[i + 1] - sa[i]), 1.0f);
    }
  }
  __syncthreads();
#pragma unroll
  for (int i = 0; i < 16; ++i) {
    int e2 = i * 256 + tid;
    int ch = e2 >> 6, lb = e2 & 63;
    out[((size_t)pb * 64 + ch) * R2_ + bin0 + lb] = tile[lb][ch];
  }
}

extern "C" void kernel_launch(void* const* d_in, const int* in_sizes, int n_in,
                              void* d_out, int out_size, void* d_ws, size_t ws_size,
                              hipStream_t stream) {
  const float* p    = (const float*)d_in[0];
  const float* fcw  = (const float*)d_in[1];
  const float* fcb  = (const float*)d_in[2];
  const float* bw0  = (const float*)d_in[3];
  const float* bb0  = (const float*)d_in[4];
  const float* bw1  = (const float*)d_in[5];
  const float* bb1  = (const float*)d_in[6];
  const float* bws  = (const float*)d_in[7];
  const float* fccw = (const float*)d_in[8];
  const float* fccb = (const float*)d_in[9];
  float* out = (float*)d_out;

  char* ws = (char*)d_ws;
  const size_t P1_LAYER = 8 * 8 * 64 * 8;               // shorts
  const size_t P2_LAYER = 12 * 8 * 64 * 8;              // shorts

  size_t off = 0;
  unsigned short* netA = (unsigned short*)(ws + off); off += (size_t)BTOT * 128 * 2;
  unsigned short* cbuf = (unsigned short*)(ws + off); off += (size_t)BTOT * 64 * 2;
  int*   idx  = (int*)(ws + off);   off += (size_t)3 * BTOT * 4;
  unsigned short* P1 = (unsigned short*)(ws + off); off += 5 * P1_LAYER * 2;
  unsigned short* P2 = (unsigned short*)(ws + off); off += 5 * P2_LAYER * 2;
  unsigned short* P3 = (unsigned short*)(ws + off); off += (size_t)16 * 64 * 8 * 2;
  int* cntb   = (int*)(ws + off); off += (size_t)3 * NBIN * 4;
  int* starts = (int*)(ws + off); off += (size_t)3 * (NBIN + 1) * 4;
  int* cursor = (int*)(ws + off); off += (size_t)3 * NBIN * 4;
  int* plist  = (int*)(ws + off); off += (size_t)3 * BTOT * 4;
  off = (off + 255) & ~(size_t)255;
  unsigned short* seg = (unsigned short*)(ws + off); // 3*NBIN*128*2 = 50.3 MiB
  unsigned short* poolB = seg;       // fc_pos B-half; dead before first poolmax

  k_idx<<<BTOT / 256, 256, 0, stream>>>(p, idx);
  hipMemsetAsync(cntb, 0, (size_t)3 * NBIN * 4, stream);
  k_count<<<3 * BTOT / 256, 256, 0, stream>>>(idx, cntb);
  k_scan<<<3, 1024, 0, stream>>>(cntb, starts, cursor);
  k_place<<<3 * BTOT / 256, 256, 0, stream>>>(idx, cursor, plist);
  k_pack<<<200, 256, 0, stream>>>(bw0, bw1, bws, P1, P2);
  k_packc<<<4, 256, 0, stream>>>(fccw, P3);
  k_fcpos<<<BTOT, 256, 0, stream>>>(p, fcw, fcb, netA, poolB);

  for (int blk = 0; blk < 5; ++blk) {
    if (blk > 0) {
      dim3 g(NBIN / 32, 3);
      k_poolmax<<<g, 256, 0, stream>>>(netA, starts, plist, seg);
    }
    k_resblock<<<BTOT / 32, 256, 0, stream>>>(
        netA, seg, idx, (blk > 0) ? 1 : 0,
        P1 + (size_t)blk * P1_LAYER, P2 + (size_t)blk * P2_LAYER,
        bb0 + (size_t)blk * 128, bb1 + (size_t)blk * 128,
        P3, fccb, (blk == 4) ? cbuf : (unsigned short*)nullptr);
  }

  dim3 gm(R2_ / 64, 12);
  k_meanout<<<gm, 256, 0, stream>>>(cbuf, starts, plist, out);
}